// Round 1
// baseline (2990.538 us; speedup 1.0000x reference)
//
#include <hip/hip_runtime.h>
#include <math.h>

#define BB 16
#define LL 512
#define DD 768
#define HH 12
#define DHH 64
#define SPDD 5
#define MM (BB*LL)   // 8192
#define LN_EPS 1e-5f
#define CLAMP_MINV 1e-6f

// ---------------- block reduce helpers (256 threads, wave64) ----------------
__device__ __forceinline__ float block_sum(float v, float* red, int tid) {
    #pragma unroll
    for (int off = 32; off; off >>= 1) v += __shfl_down(v, off, 64);
    __syncthreads();                 // protect red from previous use
    if ((tid & 63) == 0) red[tid >> 6] = v;
    __syncthreads();
    return red[0] + red[1] + red[2] + red[3];
}

__device__ __forceinline__ float block_max(float v, float* red, int tid) {
    #pragma unroll
    for (int off = 32; off; off >>= 1) v = fmaxf(v, __shfl_down(v, off, 64));
    __syncthreads();
    if ((tid & 63) == 0) red[tid >> 6] = v;
    __syncthreads();
    return fmaxf(fmaxf(red[0], red[1]), fmaxf(red[2], red[3]));
}

// ---------------- 128x128x16 fp32 SGEMM, 256 threads, 8x8 per thread -------
// C = (A1 (+ A2)) @ W + bias.  A: [MM, DD], W: [DD, DD].
// BHLD_OUT: write C[m][n] to [B,H,L,DH] at ((b*H+h)*L+l)*DH+d  (m=b*L+l, n=h*64+d)
// else flat [MM, DD].
template<bool ADD_A2, bool BHLD_OUT>
__global__ __launch_bounds__(256) void gemm_kernel(
    const float* __restrict__ A1, const float* __restrict__ A2,
    const float* __restrict__ W, const float* __restrict__ bias,
    float* __restrict__ out)
{
    const int BM = 128, BN = 128, BK = 16;
    __shared__ float As[BK][BM + 4];
    __shared__ float Bs[BK][BN + 4];
    const int bx = blockIdx.x;          // N block: 0..5
    const int by = blockIdx.y;          // M block: 0..63
    const int tid = threadIdx.x;
    const int tx = tid & 15, ty = tid >> 4;
    const int m0 = by * BM, n0 = bx * BN;

    float c[8][8] = {};

    for (int k0 = 0; k0 < DD; k0 += BK) {
        // --- load A tile (transposed into As[k][m]) ---
        {
            const int row = tid >> 2;          // 0..63
            const int kv  = (tid & 3) * 4;     // 0,4,8,12
            #pragma unroll
            for (int r = 0; r < 2; ++r) {
                const int m = m0 + row + r * 64;
                float4 v = *(const float4*)(A1 + (size_t)m * DD + k0 + kv);
                if (ADD_A2) {
                    const float4 b4 = *(const float4*)(A2 + (size_t)m * DD + k0 + kv);
                    v.x += b4.x; v.y += b4.y; v.z += b4.z; v.w += b4.w;
                }
                As[kv + 0][row + r * 64] = v.x;
                As[kv + 1][row + r * 64] = v.y;
                As[kv + 2][row + r * 64] = v.z;
                As[kv + 3][row + r * 64] = v.w;
            }
        }
        // --- load W tile ---
        {
            const int k  = tid >> 5;           // 0..7
            const int nv = (tid & 31) * 4;     // 0..124
            #pragma unroll
            for (int r = 0; r < 2; ++r) {
                *(float4*)(&Bs[k + r * 8][nv]) =
                    *(const float4*)(W + (size_t)(k0 + k + r * 8) * DD + n0 + nv);
            }
        }
        __syncthreads();

        #pragma unroll
        for (int kk = 0; kk < BK; ++kk) {
            float a[8], b[8];
            *(float4*)(a)     = *(const float4*)&As[kk][ty * 4];
            *(float4*)(a + 4) = *(const float4*)&As[kk][64 + ty * 4];
            *(float4*)(b)     = *(const float4*)&Bs[kk][tx * 4];
            *(float4*)(b + 4) = *(const float4*)&Bs[kk][64 + tx * 4];
            #pragma unroll
            for (int i = 0; i < 8; ++i)
                #pragma unroll
                for (int j = 0; j < 8; ++j)
                    c[i][j] += a[i] * b[j];
        }
        __syncthreads();
    }

    // --- epilogue ---
    #pragma unroll
    for (int i = 0; i < 8; ++i) {
        const int m = m0 + ((i < 4) ? (ty * 4 + i) : (64 + ty * 4 + i - 4));
        #pragma unroll
        for (int jj = 0; jj < 2; ++jj) {
            const int n = n0 + jj * 64 + tx * 4;
            float4 r;
            r.x = c[i][jj * 4 + 0] + bias[n + 0];
            r.y = c[i][jj * 4 + 1] + bias[n + 1];
            r.z = c[i][jj * 4 + 2] + bias[n + 2];
            r.w = c[i][jj * 4 + 3] + bias[n + 3];
            size_t idx;
            if (BHLD_OUT) {
                const int b_ = m / LL, l = m % LL;
                const int h = n >> 6, d = n & 63;
                idx = ((size_t)(b_ * HH + h) * LL + l) * DHH + d;
            } else {
                idx = (size_t)m * DD + n;
            }
            *(float4*)(out + idx) = r;
        }
    }
}

// ---------------- attention: one block per (b,h,l) --------------------------
// Q,K,V in [B,H,L,DH].  out: [B,L,D] with col = h*64+d.
__global__ __launch_bounds__(256) void attn_kernel(
    const float* __restrict__ Q, const float* __restrict__ K,
    const float* __restrict__ V, const float* __restrict__ ploc,
    const float* __restrict__ Wloc, const float* __restrict__ bloc,
    float* __restrict__ out)
{
    const int l = blockIdx.x, h = blockIdx.y, b = blockIdx.z;
    const int tid = threadIdx.x;

    __shared__ float q_s[DHH];
    __shared__ float sc[LL];
    __shared__ float red[4];
    __shared__ float wloc_s[SPDD];
    __shared__ float part[4][DHH];

    const size_t bh = (size_t)b * HH + h;
    if (tid < DHH)  q_s[tid]    = Q[(bh * LL + l) * DHH + tid];
    if (tid < SPDD) wloc_s[tid] = Wloc[tid * HH + h];
    __syncthreads();

    const float scale = 0.125f;   // 1/sqrt(64)
    const float bl = bloc[h];
    const float* Kb = K + bh * LL * DHH;
    const float* pl = ploc + ((size_t)b * LL + l) * LL * SPDD;

    // phase 1: scores + spatial log-bias
    for (int t = tid; t < LL; t += 256) {
        const float* kp = Kb + t * DHH;
        float s = 0.f;
        #pragma unroll
        for (int d = 0; d < DHH; d += 4) {
            const float4 k4 = *(const float4*)(kp + d);
            s += q_s[d] * k4.x + q_s[d + 1] * k4.y + q_s[d + 2] * k4.z + q_s[d + 3] * k4.w;
        }
        s *= scale;
        const float* pp = pl + (size_t)t * SPDD;
        float la = bl;
        #pragma unroll
        for (int si = 0; si < SPDD; ++si) la += pp[si] * wloc_s[si];
        la = fmaxf(la, 0.f);            // relu
        la = fmaxf(la, CLAMP_MINV);     // clip
        sc[t] = s + __logf(la);
    }
    __syncthreads();

    // softmax
    float m = -1e30f;
    for (int t = tid; t < LL; t += 256) m = fmaxf(m, sc[t]);
    m = block_max(m, red, tid);

    float ssum = 0.f;
    for (int t = tid; t < LL; t += 256) {
        const float e = __expf(sc[t] - m);
        sc[t] = e;
        ssum += e;
    }
    const float denom = block_sum(ssum, red, tid);  // internal sync makes sc visible
    const float inv = 1.f / denom;

    // phase 2: P @ V  — thread = (chunk, d)
    const int d = tid & 63, chunk = tid >> 6;
    const float* Vb = V + bh * LL * DHH;
    float acc = 0.f;
    const int t0 = chunk * 128, t1 = t0 + 128;
    for (int t = t0; t < t1; ++t)
        acc += sc[t] * Vb[(size_t)t * DHH + d];
    part[chunk][d] = acc;
    __syncthreads();

    if (tid < DHH) {
        const float o = (part[0][tid] + part[1][tid] + part[2][tid] + part[3][tid]) * inv;
        out[((size_t)b * LL + l) * DD + h * DHH + tid] = o;
    }
}

// ---------------- residual + LayerNorm --------------------------------------
__global__ __launch_bounds__(256) void ln_kernel(
    const float* __restrict__ x, const float* __restrict__ tgt,
    const float* __restrict__ g, const float* __restrict__ bta,
    float* __restrict__ out)
{
    const int row = blockIdx.x;
    const int tid = threadIdx.x;
    __shared__ float red[4];

    const float* xp = x + (size_t)row * DD;
    const float* tp = tgt + (size_t)row * DD;

    float vals[3];
    float s = 0.f;
    #pragma unroll
    for (int i = 0; i < 3; ++i) {
        const float v = xp[tid + i * 256] + tp[tid + i * 256];
        vals[i] = v;
        s += v;
    }
    s = block_sum(s, red, tid);
    const float mu = s * (1.f / 768.f);

    float vs = 0.f;
    #pragma unroll
    for (int i = 0; i < 3; ++i) {
        const float dv = vals[i] - mu;
        vs += dv * dv;
    }
    vs = block_sum(vs, red, tid);
    const float rstd = rsqrtf(vs * (1.f / 768.f) + LN_EPS);

    #pragma unroll
    for (int i = 0; i < 3; ++i) {
        const int cidx = tid + i * 256;
        out[(size_t)row * DD + cidx] = g[cidx] * (vals[i] - mu) * rstd + bta[cidx];
    }
}

// ---------------- launch -----------------------------------------------------
extern "C" void kernel_launch(void* const* d_in, const int* in_sizes, int n_in,
                              void* d_out, int out_size, void* d_ws, size_t ws_size,
                              hipStream_t stream) {
    const float* tgt   = (const float*)d_in[0];
    const float* qpos  = (const float*)d_in[1];
    const float* ploc  = (const float*)d_in[2];
    const float* Wq    = (const float*)d_in[3];
    const float* bq    = (const float*)d_in[4];
    const float* Wk    = (const float*)d_in[5];
    const float* bk    = (const float*)d_in[6];
    const float* Wv    = (const float*)d_in[7];
    const float* bv    = (const float*)d_in[8];
    const float* Wo    = (const float*)d_in[9];
    const float* bo    = (const float*)d_in[10];
    const float* Wloc  = (const float*)d_in[11];
    const float* bloc  = (const float*)d_in[12];
    const float* ln_g  = (const float*)d_in[13];
    const float* ln_b  = (const float*)d_in[14];

    float* ws = (float*)d_ws;
    const size_t NQ = (size_t)MM * DD;   // 6291456
    float* qbuf  = ws;
    float* kbuf  = ws + NQ;
    float* vbuf  = ws + 2 * NQ;
    float* aobuf = ws + 3 * NQ;
    float* pbuf  = qbuf;                 // reuse Q slot for proj output

    dim3 gg(DD / 128, MM / 128);         // (6, 64)
    gemm_kernel<true,  true ><<<gg, 256, 0, stream>>>(tgt, qpos, Wq, bq, qbuf);
    gemm_kernel<true,  true ><<<gg, 256, 0, stream>>>(tgt, qpos, Wk, bk, kbuf);
    gemm_kernel<false, true ><<<gg, 256, 0, stream>>>(tgt, nullptr, Wv, bv, vbuf);

    dim3 ga(LL, HH, BB);
    attn_kernel<<<ga, 256, 0, stream>>>(qbuf, kbuf, vbuf, ploc, Wloc, bloc, aobuf);

    gemm_kernel<false, false><<<gg, 256, 0, stream>>>(aobuf, nullptr, Wo, bo, pbuf);

    ln_kernel<<<MM, 256, 0, stream>>>(pbuf, tgt, ln_g, ln_b, (float*)d_out);
}

// Round 2
// 921.712 us; speedup vs baseline: 3.2445x; 3.2445x over previous
//
#include <hip/hip_runtime.h>
#include <math.h>

#define BB 16
#define LL 512
#define DD 768
#define HH 12
#define DHH 64
#define SPDD 5
#define MM (BB*LL)   // 8192
#define LN_EPS 1e-5f
#define CLAMP_MINV 1e-6f

typedef __attribute__((ext_vector_type(8))) short bf8_t;
typedef __attribute__((ext_vector_type(4))) float f4_t;

__device__ __forceinline__ short f2bf(float x) {
    unsigned u = __builtin_bit_cast(unsigned, x);
    unsigned r = (u + 0x7FFFu + ((u >> 16) & 1u)) >> 16;
    return (short)r;
}

// ---------------- block reduce helpers (256 threads, wave64) ----------------
__device__ __forceinline__ float block_sum(float v, float* red, int tid) {
    #pragma unroll
    for (int off = 32; off; off >>= 1) v += __shfl_down(v, off, 64);
    __syncthreads();
    if ((tid & 63) == 0) red[tid >> 6] = v;
    __syncthreads();
    return red[0] + red[1] + red[2] + red[3];
}

// ---------------- 128x128x16 fp32 SGEMM, 256 threads, 8x8 per thread -------
// C = (A1 (+ A2)) @ W + bias.
// MODE 0: fp32 out, flat [MM,DD]
// MODE 1: bf16 out, [B,H,L,DH]   (Q, K)
// MODE 2: bf16 out, [B,H,DH,L]   (V transposed)
template<bool ADD_A2, int MODE>
__global__ __launch_bounds__(256) void gemm_kernel(
    const float* __restrict__ A1, const float* __restrict__ A2,
    const float* __restrict__ W, const float* __restrict__ bias,
    void* __restrict__ outv)
{
    const int BM = 128, BN = 128, BK = 16;
    __shared__ float As[BK][BM + 4];
    __shared__ float Bs[BK][BN + 4];
    const int bx = blockIdx.x;
    const int by = blockIdx.y;
    const int tid = threadIdx.x;
    const int tx = tid & 15, ty = tid >> 4;
    const int m0 = by * BM, n0 = bx * BN;

    float c[8][8] = {};

    for (int k0 = 0; k0 < DD; k0 += BK) {
        {
            const int row = tid >> 2;
            const int kv  = (tid & 3) * 4;
            #pragma unroll
            for (int r = 0; r < 2; ++r) {
                const int m = m0 + row + r * 64;
                float4 v = *(const float4*)(A1 + (size_t)m * DD + k0 + kv);
                if (ADD_A2) {
                    const float4 b4 = *(const float4*)(A2 + (size_t)m * DD + k0 + kv);
                    v.x += b4.x; v.y += b4.y; v.z += b4.z; v.w += b4.w;
                }
                As[kv + 0][row + r * 64] = v.x;
                As[kv + 1][row + r * 64] = v.y;
                As[kv + 2][row + r * 64] = v.z;
                As[kv + 3][row + r * 64] = v.w;
            }
        }
        {
            const int k  = tid >> 5;
            const int nv = (tid & 31) * 4;
            #pragma unroll
            for (int r = 0; r < 2; ++r) {
                *(float4*)(&Bs[k + r * 8][nv]) =
                    *(const float4*)(W + (size_t)(k0 + k + r * 8) * DD + n0 + nv);
            }
        }
        __syncthreads();

        #pragma unroll
        for (int kk = 0; kk < BK; ++kk) {
            float a[8], b[8];
            *(float4*)(a)     = *(const float4*)&As[kk][ty * 4];
            *(float4*)(a + 4) = *(const float4*)&As[kk][64 + ty * 4];
            *(float4*)(b)     = *(const float4*)&Bs[kk][tx * 4];
            *(float4*)(b + 4) = *(const float4*)&Bs[kk][64 + tx * 4];
            #pragma unroll
            for (int i = 0; i < 8; ++i)
                #pragma unroll
                for (int j = 0; j < 8; ++j)
                    c[i][j] += a[i] * b[j];
        }
        __syncthreads();
    }

    #pragma unroll
    for (int i = 0; i < 8; ++i) {
        const int m = m0 + ((i < 4) ? (ty * 4 + i) : (64 + ty * 4 + i - 4));
        #pragma unroll
        for (int jj = 0; jj < 2; ++jj) {
            const int n = n0 + jj * 64 + tx * 4;
            float4 r;
            r.x = c[i][jj * 4 + 0] + bias[n + 0];
            r.y = c[i][jj * 4 + 1] + bias[n + 1];
            r.z = c[i][jj * 4 + 2] + bias[n + 2];
            r.w = c[i][jj * 4 + 3] + bias[n + 3];
            if (MODE == 0) {
                *(float4*)((float*)outv + (size_t)m * DD + n) = r;
            } else {
                const int b_ = m / LL, l = m % LL;
                const int h = n >> 6, d = n & 63;
                short* o = (short*)outv;
                if (MODE == 1) {
                    const size_t idx = ((size_t)(b_ * HH + h) * LL + l) * DHH + d;
                    short4 s;
                    s.x = f2bf(r.x); s.y = f2bf(r.y); s.z = f2bf(r.z); s.w = f2bf(r.w);
                    *(short4*)(o + idx) = s;
                } else {
                    const size_t base = ((size_t)(b_ * HH + h) * DHH + d) * LL + l;
                    o[base]            = f2bf(r.x);
                    o[base + LL]       = f2bf(r.y);
                    o[base + 2 * LL]   = f2bf(r.z);
                    o[base + 3 * LL]   = f2bf(r.w);
                }
            }
        }
    }
}

// ---------------- flash-style MFMA attention --------------------------------
// Q,K bf16 [B,H,L,DH]; Vt bf16 [B,H,DH,L]; out fp32 [B,L,D].
// Block: (qtile, h, b). 256 thr = 4 waves; wave w owns q rows q0+16w..+15.
// MFMA 16x16x32 bf16. A-layout: m=lane&15, k=quad*8+j. C/D: col=lane&15,
// row=quad*4+reg.
__global__ __launch_bounds__(256) void attn_mfma(
    const short* __restrict__ Q, const short* __restrict__ K,
    const short* __restrict__ Vt, const float* __restrict__ ploc,
    const float* __restrict__ Wloc, const float* __restrict__ bloc,
    float* __restrict__ out)
{
    __shared__ short Ks[64 * 64];      // [t][d]
    __shared__ short Vs[64 * 64];      // [d][t]
    __shared__ float bs[64 * 65];      // [l][t] log-bias, padded stride
    __shared__ short Ps[4][16 * 64];   // per-wave P staging [row][t]

    const int qt = blockIdx.x, h = blockIdx.y, b = blockIdx.z;
    const int tid = threadIdx.x;
    const int w = tid >> 6, lane = tid & 63;
    const int quad = lane >> 4, l16 = lane & 15;
    const int q0 = qt * 64;
    const size_t bh = (size_t)b * HH + h;

    float wl[SPDD];
    #pragma unroll
    for (int s = 0; s < SPDD; ++s) wl[s] = Wloc[s * HH + h];
    const float blc = bloc[h];

    // Q fragments (this wave's 16 rows), kept in registers all loop
    const int qr = q0 + w * 16 + l16;
    const bf8_t aq0 = *(const bf8_t*)(Q + (bh * LL + qr) * DHH + quad * 8);
    const bf8_t aq1 = *(const bf8_t*)(Q + (bh * LL + qr) * DHH + quad * 8 + 32);

    f4_t o[4];
    #pragma unroll
    for (int dj = 0; dj < 4; ++dj) o[dj] = (f4_t){0.f, 0.f, 0.f, 0.f};
    float m_row[4], l_row[4];
    #pragma unroll
    for (int r = 0; r < 4; ++r) { m_row[r] = -1e30f; l_row[r] = 0.f; }

    const short* Kg = K  + bh * LL * DHH;   // [512][64], tile is flat-contiguous
    const short* Vg = Vt + bh * DHH * LL;   // [64][512]

    for (int t0 = 0; t0 < LL; t0 += 64) {
        __syncthreads();   // prev iteration's reads done before restaging
        // stage K tile: flat 4096 shorts
        {
            const short* src = Kg + t0 * DHH + tid * 16;
            *(bf8_t*)(Ks + tid * 16)     = *(const bf8_t*)(src);
            *(bf8_t*)(Ks + tid * 16 + 8) = *(const bf8_t*)(src + 8);
        }
        // stage V^T tile rows
        {
            const int d = tid >> 2, ch = (tid & 3) * 16;
            const short* src = Vg + (size_t)d * LL + t0 + ch;
            *(bf8_t*)(Vs + d * 64 + ch)     = *(const bf8_t*)(src);
            *(bf8_t*)(Vs + d * 64 + ch + 8) = *(const bf8_t*)(src + 8);
        }
        // stage spatial log-bias tile
        {
            const int l = tid >> 2, ts = (tid & 3) * 16;
            const float* pp = ploc + (((size_t)b * LL + q0 + l) * LL + t0 + ts) * SPDD;
            #pragma unroll
            for (int i = 0; i < 16; ++i) {
                float la = blc;
                #pragma unroll
                for (int s = 0; s < SPDD; ++s) la += pp[i * SPDD + s] * wl[s];
                la = fmaxf(fmaxf(la, 0.f), CLAMP_MINV);
                bs[l * 65 + ts + i] = __logf(la);
            }
        }
        __syncthreads();

        // S = Q K^T : 16 rows x 64 cols per wave
        f4_t sv[4];
        #pragma unroll
        for (int j = 0; j < 4; ++j) {
            const bf8_t b0 = *(const bf8_t*)(Ks + (j * 16 + l16) * 64 + quad * 8);
            const bf8_t b1 = *(const bf8_t*)(Ks + (j * 16 + l16) * 64 + quad * 8 + 32);
            f4_t c = (f4_t){0.f, 0.f, 0.f, 0.f};
            c = __builtin_amdgcn_mfma_f32_16x16x32_bf16(aq0, b0, c, 0, 0, 0);
            c = __builtin_amdgcn_mfma_f32_16x16x32_bf16(aq1, b1, c, 0, 0, 0);
            sv[j] = c;
        }
        // scale + spatial bias
        #pragma unroll
        for (int j = 0; j < 4; ++j)
            #pragma unroll
            for (int r = 0; r < 4; ++r) {
                const int lrel = w * 16 + quad * 4 + r;
                sv[j][r] = sv[j][r] * 0.125f + bs[lrel * 65 + j * 16 + l16];
            }
        // online softmax per row (rows live across the 16 lanes of this quad)
        #pragma unroll
        for (int r = 0; r < 4; ++r) {
            float mx = fmaxf(fmaxf(sv[0][r], sv[1][r]), fmaxf(sv[2][r], sv[3][r]));
            mx = fmaxf(mx, __shfl_xor(mx, 1, 16));
            mx = fmaxf(mx, __shfl_xor(mx, 2, 16));
            mx = fmaxf(mx, __shfl_xor(mx, 4, 16));
            mx = fmaxf(mx, __shfl_xor(mx, 8, 16));
            const float mn = fmaxf(m_row[r], mx);
            const float al = __expf(m_row[r] - mn);
            m_row[r] = mn;
            float rs = 0.f;
            #pragma unroll
            for (int j = 0; j < 4; ++j) {
                const float p = __expf(sv[j][r] - mn);
                sv[j][r] = p;
                rs += p;
            }
            rs += __shfl_xor(rs, 1, 16);
            rs += __shfl_xor(rs, 2, 16);
            rs += __shfl_xor(rs, 4, 16);
            rs += __shfl_xor(rs, 8, 16);
            l_row[r] = l_row[r] * al + rs;
            #pragma unroll
            for (int dj = 0; dj < 4; ++dj) o[dj][r] *= al;
        }
        // P: C-layout -> LDS -> A-layout (per-wave region, wave-ordered, no barrier)
        short* Pw = Ps[w];
        #pragma unroll
        for (int r = 0; r < 4; ++r)
            #pragma unroll
            for (int j = 0; j < 4; ++j)
                Pw[(quad * 4 + r) * 64 + j * 16 + l16] = f2bf(sv[j][r]);

        const bf8_t ap0 = *(const bf8_t*)(Pw + l16 * 64 + quad * 8);
        const bf8_t ap1 = *(const bf8_t*)(Pw + l16 * 64 + quad * 8 + 32);
        #pragma unroll
        for (int dj = 0; dj < 4; ++dj) {
            const bf8_t b0 = *(const bf8_t*)(Vs + (dj * 16 + l16) * 64 + quad * 8);
            const bf8_t b1 = *(const bf8_t*)(Vs + (dj * 16 + l16) * 64 + quad * 8 + 32);
            o[dj] = __builtin_amdgcn_mfma_f32_16x16x32_bf16(ap0, b0, o[dj], 0, 0, 0);
            o[dj] = __builtin_amdgcn_mfma_f32_16x16x32_bf16(ap1, b1, o[dj], 0, 0, 0);
        }
    }

    // epilogue: normalize and write fp32 [B,L,D]
    #pragma unroll
    for (int r = 0; r < 4; ++r) {
        const int l = q0 + w * 16 + quad * 4 + r;
        const float inv = 1.f / l_row[r];
        #pragma unroll
        for (int dj = 0; dj < 4; ++dj)
            out[((size_t)b * LL + l) * DD + h * DHH + dj * 16 + l16] = o[dj][r] * inv;
    }
}

// ---------------- residual + LayerNorm --------------------------------------
__global__ __launch_bounds__(256) void ln_kernel(
    const float* __restrict__ x, const float* __restrict__ tgt,
    const float* __restrict__ g, const float* __restrict__ bta,
    float* __restrict__ out)
{
    const int row = blockIdx.x;
    const int tid = threadIdx.x;
    __shared__ float red[4];

    const float* xp = x + (size_t)row * DD;
    const float* tp = tgt + (size_t)row * DD;

    float vals[3];
    float s = 0.f;
    #pragma unroll
    for (int i = 0; i < 3; ++i) {
        const float v = xp[tid + i * 256] + tp[tid + i * 256];
        vals[i] = v;
        s += v;
    }
    s = block_sum(s, red, tid);
    const float mu = s * (1.f / 768.f);

    float vs = 0.f;
    #pragma unroll
    for (int i = 0; i < 3; ++i) {
        const float dv = vals[i] - mu;
        vs += dv * dv;
    }
    vs = block_sum(vs, red, tid);
    const float rstd = rsqrtf(vs * (1.f / 768.f) + LN_EPS);

    #pragma unroll
    for (int i = 0; i < 3; ++i) {
        const int cidx = tid + i * 256;
        out[(size_t)row * DD + cidx] = g[cidx] * (vals[i] - mu) * rstd + bta[cidx];
    }
}

// ---------------- launch -----------------------------------------------------
extern "C" void kernel_launch(void* const* d_in, const int* in_sizes, int n_in,
                              void* d_out, int out_size, void* d_ws, size_t ws_size,
                              hipStream_t stream) {
    const float* tgt   = (const float*)d_in[0];
    const float* qpos  = (const float*)d_in[1];
    const float* ploc  = (const float*)d_in[2];
    const float* Wq    = (const float*)d_in[3];
    const float* bq    = (const float*)d_in[4];
    const float* Wk    = (const float*)d_in[5];
    const float* bk    = (const float*)d_in[6];
    const float* Wv    = (const float*)d_in[7];
    const float* bv    = (const float*)d_in[8];
    const float* Wo    = (const float*)d_in[9];
    const float* bo    = (const float*)d_in[10];
    const float* Wloc  = (const float*)d_in[11];
    const float* bloc  = (const float*)d_in[12];
    const float* ln_g  = (const float*)d_in[13];
    const float* ln_b  = (const float*)d_in[14];

    const size_t NQ = (size_t)MM * DD;   // 6291456
    short* qb    = (short*)d_ws;
    short* kb    = qb + NQ;
    short* vtb   = kb + NQ;
    float* aobuf = (float*)(vtb + NQ);
    float* pbuf  = aobuf + NQ;

    dim3 gg(DD / 128, MM / 128);         // (6, 64)
    gemm_kernel<true,  1><<<gg, 256, 0, stream>>>(tgt, qpos, Wq, bq, qb);
    gemm_kernel<true,  1><<<gg, 256, 0, stream>>>(tgt, qpos, Wk, bk, kb);
    gemm_kernel<false, 2><<<gg, 256, 0, stream>>>(tgt, nullptr, Wv, bv, vtb);

    dim3 ga(LL / 64, HH, BB);            // (8, 12, 16)
    attn_mfma<<<ga, 256, 0, stream>>>(qb, kb, vtb, ploc, Wloc, bloc, aobuf);

    gemm_kernel<false, 0><<<gg, 256, 0, stream>>>(aobuf, nullptr, Wo, bo, pbuf);

    ln_kernel<<<MM, 256, 0, stream>>>(pbuf, tgt, ln_g, ln_b, (float*)d_out);
}

// Round 3
// 410.988 us; speedup vs baseline: 7.2765x; 2.2427x over previous
//
#include <hip/hip_runtime.h>
#include <math.h>

#define BB 16
#define LL 512
#define DD 768
#define HH 12
#define DHH 64
#define SPDD 5
#define MM (BB*LL)   // 8192
#define LN_EPS 1e-5f
#define CLAMP_MINV 1e-6f

typedef __attribute__((ext_vector_type(8))) short bf8_t;
typedef __attribute__((ext_vector_type(4))) float f4_t;

__device__ __forceinline__ short f2bf(float x) {
    unsigned u = __builtin_bit_cast(unsigned, x);
    unsigned r = (u + 0x7FFFu + ((u >> 16) & 1u)) >> 16;
    return (short)r;
}

__device__ __forceinline__ void gld16(const short* g, short* l) {
    __builtin_amdgcn_global_load_lds(
        (const __attribute__((address_space(1))) unsigned int*)g,
        (__attribute__((address_space(3))) unsigned int*)l,
        16, 0, 0);
}

// ---------------- block reduce (256 threads, wave64) ------------------------
__device__ __forceinline__ float block_sum(float v, float* red, int tid) {
    #pragma unroll
    for (int off = 32; off; off >>= 1) v += __shfl_down(v, off, 64);
    __syncthreads();
    if ((tid & 63) == 0) red[tid >> 6] = v;
    __syncthreads();
    return red[0] + red[1] + red[2] + red[3];
}

// ---------------- weight transpose + cast: Wt[n][k] = bf16(W[k][n]) ---------
__global__ __launch_bounds__(256) void wtrans_kernel(
    const float* __restrict__ W0, const float* __restrict__ W1,
    const float* __restrict__ W2, const float* __restrict__ W3,
    short* __restrict__ O0, short* __restrict__ O1,
    short* __restrict__ O2, short* __restrict__ O3)
{
    const float* W; short* O;
    switch (blockIdx.z) {
        case 0: W = W0; O = O0; break;
        case 1: W = W1; O = O1; break;
        case 2: W = W2; O = O2; break;
        default: W = W3; O = O3; break;
    }
    __shared__ float T[64][65];
    const int n0 = blockIdx.x * 64, k0 = blockIdx.y * 64;
    const int tid = threadIdx.x;
    {
        const int kk = tid >> 4, nv = (tid & 15) * 4;
        #pragma unroll
        for (int i = 0; i < 4; ++i) {
            const int k = kk + i * 16;
            const float4 v = *(const float4*)(W + (size_t)(k0 + k) * DD + n0 + nv);
            T[k][nv + 0] = v.x; T[k][nv + 1] = v.y;
            T[k][nv + 2] = v.z; T[k][nv + 3] = v.w;
        }
    }
    __syncthreads();
    {
        const int n = tid >> 2, kc = (tid & 3) * 16;
        short tmp[16];
        #pragma unroll
        for (int i = 0; i < 16; ++i) tmp[i] = f2bf(T[kc + i][n]);
        short* dst = O + (size_t)(n0 + n) * DD + k0 + kc;
        *(bf8_t*)dst       = *(bf8_t*)tmp;
        *(bf8_t*)(dst + 8) = *(bf8_t*)(tmp + 8);
    }
}

// ---------------- cast inputs: aqk = bf16(tgt+qpos), av = bf16(tgt) ---------
__global__ __launch_bounds__(256) void cast_inputs(
    const float* __restrict__ tgt, const float* __restrict__ qpos,
    short* __restrict__ aqk, short* __restrict__ av)
{
    const size_t base = ((size_t)blockIdx.x * 256 + threadIdx.x) * 8;
    const float4 t0 = *(const float4*)(tgt + base);
    const float4 t1 = *(const float4*)(tgt + base + 4);
    const float4 p0 = *(const float4*)(qpos + base);
    const float4 p1 = *(const float4*)(qpos + base + 4);
    short v[8], q[8];
    v[0] = f2bf(t0.x); v[1] = f2bf(t0.y); v[2] = f2bf(t0.z); v[3] = f2bf(t0.w);
    v[4] = f2bf(t1.x); v[5] = f2bf(t1.y); v[6] = f2bf(t1.z); v[7] = f2bf(t1.w);
    q[0] = f2bf(t0.x + p0.x); q[1] = f2bf(t0.y + p0.y);
    q[2] = f2bf(t0.z + p0.z); q[3] = f2bf(t0.w + p0.w);
    q[4] = f2bf(t1.x + p1.x); q[5] = f2bf(t1.y + p1.y);
    q[6] = f2bf(t1.z + p1.z); q[7] = f2bf(t1.w + p1.w);
    *(bf8_t*)(av + base)  = *(bf8_t*)v;
    *(bf8_t*)(aqk + base) = *(bf8_t*)q;
}

// ---------------- bf16 MFMA GEMM: C = A @ Wt^T + bias -----------------------
// A: bf16 [MM, DD].  Wt: bf16 [N, K] (pre-transposed).  Tile 128x128, BK=64.
// 256 thr = 4 waves, 2x2 wave grid, each wave 4x4 tiles of 16x16x32 MFMA.
// LDS XOR swizzle: logical 16B chunk c of row r stored at chunk c ^ (r&7).
// MODE 0: fp32 out flat [MM,DD]; MODE 1: bf16 [B,H,L,DH]; MODE 2: bf16 [B,H,DH,L].
template<int MODE, bool FUSE>
__global__ __launch_bounds__(256) void gemm_mfma(
    const short* __restrict__ A,
    const short* __restrict__ Wa, const float* __restrict__ ba, void* __restrict__ oa,
    const short* __restrict__ Wb, const float* __restrict__ bb, void* __restrict__ ob)
{
    __shared__ short As[128 * 64];
    __shared__ short Bs[128 * 64];
    int bx = blockIdx.x;
    const int by = blockIdx.y;
    const short* Wt; const float* bias; void* out;
    if (FUSE && bx >= 6) { Wt = Wb; bias = bb; out = ob; bx -= 6; }
    else                 { Wt = Wa; bias = ba; out = oa; }
    const int n0 = bx * 128, m0 = by * 128;
    const int tid = threadIdx.x;
    const int w = tid >> 6, lane = tid & 63;
    const int quad = lane >> 4, l16 = lane & 15;
    const int wm = w & 1, wn = w >> 1;

    // staging slot: row sr+ra*32, physical chunk sp; logical chunk sp^(r&7)
    const int sr = w * 8 + (lane >> 3);
    const int sp = lane & 7;

    f4_t acc[4][4];
    #pragma unroll
    for (int i = 0; i < 4; ++i)
        #pragma unroll
        for (int j = 0; j < 4; ++j) acc[i][j] = (f4_t){0.f, 0.f, 0.f, 0.f};

    for (int k0 = 0; k0 < DD; k0 += 64) {
        __syncthreads();
        #pragma unroll
        for (int ra = 0; ra < 4; ++ra) {
            const int r = sr + ra * 32;
            const int c = sp ^ (r & 7);
            const int ldso = ra * 2048 + w * 512 + lane * 8;
            gld16(A  + (size_t)(m0 + r) * DD + k0 + c * 8, As + ldso);
            gld16(Wt + (size_t)(n0 + r) * DD + k0 + c * 8, Bs + ldso);
        }
        __syncthreads();
        #pragma unroll
        for (int s = 0; s < 2; ++s) {
            bf8_t a[4], b[4];
            #pragma unroll
            for (int i = 0; i < 4; ++i) {
                const int rA = wm * 64 + i * 16 + l16;
                const int pA = (s * 4 + quad) ^ (rA & 7);
                a[i] = *(const bf8_t*)(As + rA * 64 + pA * 8);
                const int rB = wn * 64 + i * 16 + l16;
                const int pB = (s * 4 + quad) ^ (rB & 7);
                b[i] = *(const bf8_t*)(Bs + rB * 64 + pB * 8);
            }
            #pragma unroll
            for (int i = 0; i < 4; ++i)
                #pragma unroll
                for (int j = 0; j < 4; ++j)
                    acc[i][j] = __builtin_amdgcn_mfma_f32_16x16x32_bf16(a[i], b[j], acc[i][j], 0, 0, 0);
        }
    }

    // epilogue
    float bv[4];
    #pragma unroll
    for (int j = 0; j < 4; ++j) bv[j] = bias[n0 + wn * 64 + j * 16 + l16];
    #pragma unroll
    for (int i = 0; i < 4; ++i) {
        #pragma unroll
        for (int j = 0; j < 4; ++j) {
            const int n = n0 + wn * 64 + j * 16 + l16;
            #pragma unroll
            for (int r = 0; r < 4; ++r) {
                const int m = m0 + wm * 64 + i * 16 + quad * 4 + r;
                const float val = acc[i][j][r] + bv[j];
                if (MODE == 0) {
                    ((float*)out)[(size_t)m * DD + n] = val;
                } else {
                    const int b_ = m >> 9, l = m & 511;
                    const int h = n >> 6, d = n & 63;
                    if (MODE == 1)
                        ((short*)out)[(((size_t)(b_ * HH + h)) * LL + l) * DHH + d] = f2bf(val);
                    else
                        ((short*)out)[(((size_t)(b_ * HH + h)) * DHH + d) * LL + l] = f2bf(val);
                }
            }
        }
    }
}

// ---------------- flash-style MFMA attention (bf16 out) ---------------------
__global__ __launch_bounds__(256) void attn_mfma(
    const short* __restrict__ Q, const short* __restrict__ K,
    const short* __restrict__ Vt, const float* __restrict__ ploc,
    const float* __restrict__ Wloc, const float* __restrict__ bloc,
    short* __restrict__ out)
{
    __shared__ short Ks[64 * 64];      // [t][d]
    __shared__ short Vs[64 * 64];      // [d][t]
    __shared__ float bs[64 * 65];      // [l][t] log-bias
    __shared__ short Ps[4][16 * 64];   // per-wave P staging

    const int qt = blockIdx.x, h = blockIdx.y, b = blockIdx.z;
    const int tid = threadIdx.x;
    const int w = tid >> 6, lane = tid & 63;
    const int quad = lane >> 4, l16 = lane & 15;
    const int q0 = qt * 64;
    const size_t bh = (size_t)b * HH + h;

    float wl[SPDD];
    #pragma unroll
    for (int s = 0; s < SPDD; ++s) wl[s] = Wloc[s * HH + h];
    const float blc = bloc[h];

    const int qr = q0 + w * 16 + l16;
    const bf8_t aq0 = *(const bf8_t*)(Q + (bh * LL + qr) * DHH + quad * 8);
    const bf8_t aq1 = *(const bf8_t*)(Q + (bh * LL + qr) * DHH + quad * 8 + 32);

    f4_t o[4];
    #pragma unroll
    for (int dj = 0; dj < 4; ++dj) o[dj] = (f4_t){0.f, 0.f, 0.f, 0.f};
    float m_row[4], l_row[4];
    #pragma unroll
    for (int r = 0; r < 4; ++r) { m_row[r] = -1e30f; l_row[r] = 0.f; }

    const short* Kg = K  + bh * LL * DHH;
    const short* Vg = Vt + bh * DHH * LL;

    for (int t0 = 0; t0 < LL; t0 += 64) {
        __syncthreads();
        {
            const short* src = Kg + t0 * DHH + tid * 16;
            *(bf8_t*)(Ks + tid * 16)     = *(const bf8_t*)(src);
            *(bf8_t*)(Ks + tid * 16 + 8) = *(const bf8_t*)(src + 8);
        }
        {
            const int d = tid >> 2, ch = (tid & 3) * 16;
            const short* src = Vg + (size_t)d * LL + t0 + ch;
            *(bf8_t*)(Vs + d * 64 + ch)     = *(const bf8_t*)(src);
            *(bf8_t*)(Vs + d * 64 + ch + 8) = *(const bf8_t*)(src + 8);
        }
        {
            const int l = tid >> 2, ts = (tid & 3) * 16;
            const float* pp = ploc + (((size_t)b * LL + q0 + l) * LL + t0 + ts) * SPDD;
            #pragma unroll
            for (int i = 0; i < 16; ++i) {
                float la = blc;
                #pragma unroll
                for (int s = 0; s < SPDD; ++s) la += pp[i * SPDD + s] * wl[s];
                la = fmaxf(fmaxf(la, 0.f), CLAMP_MINV);
                bs[l * 65 + ts + i] = __logf(la);
            }
        }
        __syncthreads();

        f4_t sv[4];
        #pragma unroll
        for (int j = 0; j < 4; ++j) {
            const bf8_t b0 = *(const bf8_t*)(Ks + (j * 16 + l16) * 64 + quad * 8);
            const bf8_t b1 = *(const bf8_t*)(Ks + (j * 16 + l16) * 64 + quad * 8 + 32);
            f4_t c = (f4_t){0.f, 0.f, 0.f, 0.f};
            c = __builtin_amdgcn_mfma_f32_16x16x32_bf16(aq0, b0, c, 0, 0, 0);
            c = __builtin_amdgcn_mfma_f32_16x16x32_bf16(aq1, b1, c, 0, 0, 0);
            sv[j] = c;
        }
        #pragma unroll
        for (int j = 0; j < 4; ++j)
            #pragma unroll
            for (int r = 0; r < 4; ++r) {
                const int lrel = w * 16 + quad * 4 + r;
                sv[j][r] = sv[j][r] * 0.125f + bs[lrel * 65 + j * 16 + l16];
            }
        #pragma unroll
        for (int r = 0; r < 4; ++r) {
            float mx = fmaxf(fmaxf(sv[0][r], sv[1][r]), fmaxf(sv[2][r], sv[3][r]));
            mx = fmaxf(mx, __shfl_xor(mx, 1, 16));
            mx = fmaxf(mx, __shfl_xor(mx, 2, 16));
            mx = fmaxf(mx, __shfl_xor(mx, 4, 16));
            mx = fmaxf(mx, __shfl_xor(mx, 8, 16));
            const float mn = fmaxf(m_row[r], mx);
            const float al = __expf(m_row[r] - mn);
            m_row[r] = mn;
            float rs = 0.f;
            #pragma unroll
            for (int j = 0; j < 4; ++j) {
                const float p = __expf(sv[j][r] - mn);
                sv[j][r] = p;
                rs += p;
            }
            rs += __shfl_xor(rs, 1, 16);
            rs += __shfl_xor(rs, 2, 16);
            rs += __shfl_xor(rs, 4, 16);
            rs += __shfl_xor(rs, 8, 16);
            l_row[r] = l_row[r] * al + rs;
            #pragma unroll
            for (int dj = 0; dj < 4; ++dj) o[dj][r] *= al;
        }
        short* Pw = Ps[w];
        #pragma unroll
        for (int r = 0; r < 4; ++r)
            #pragma unroll
            for (int j = 0; j < 4; ++j)
                Pw[(quad * 4 + r) * 64 + j * 16 + l16] = f2bf(sv[j][r]);

        const bf8_t ap0 = *(const bf8_t*)(Pw + l16 * 64 + quad * 8);
        const bf8_t ap1 = *(const bf8_t*)(Pw + l16 * 64 + quad * 8 + 32);
        #pragma unroll
        for (int dj = 0; dj < 4; ++dj) {
            const bf8_t b0 = *(const bf8_t*)(Vs + (dj * 16 + l16) * 64 + quad * 8);
            const bf8_t b1 = *(const bf8_t*)(Vs + (dj * 16 + l16) * 64 + quad * 8 + 32);
            o[dj] = __builtin_amdgcn_mfma_f32_16x16x32_bf16(ap0, b0, o[dj], 0, 0, 0);
            o[dj] = __builtin_amdgcn_mfma_f32_16x16x32_bf16(ap1, b1, o[dj], 0, 0, 0);
        }
    }

    #pragma unroll
    for (int r = 0; r < 4; ++r) {
        const int l = q0 + w * 16 + quad * 4 + r;
        const float inv = 1.f / l_row[r];
        short* op = out + ((size_t)b * LL + l) * DD + h * DHH;
        #pragma unroll
        for (int dj = 0; dj < 4; ++dj)
            op[dj * 16 + l16] = f2bf(o[dj][r] * inv);
    }
}

// ---------------- residual + LayerNorm --------------------------------------
__global__ __launch_bounds__(256) void ln_kernel(
    const float* __restrict__ x, const float* __restrict__ tgt,
    const float* __restrict__ g, const float* __restrict__ bta,
    float* __restrict__ out)
{
    const int row = blockIdx.x;
    const int tid = threadIdx.x;
    __shared__ float red[4];

    const float* xp = x + (size_t)row * DD;
    const float* tp = tgt + (size_t)row * DD;

    float vals[3];
    float s = 0.f;
    #pragma unroll
    for (int i = 0; i < 3; ++i) {
        const float v = xp[tid + i * 256] + tp[tid + i * 256];
        vals[i] = v;
        s += v;
    }
    s = block_sum(s, red, tid);
    const float mu = s * (1.f / 768.f);

    float vs = 0.f;
    #pragma unroll
    for (int i = 0; i < 3; ++i) {
        const float dv = vals[i] - mu;
        vs += dv * dv;
    }
    vs = block_sum(vs, red, tid);
    const float rstd = rsqrtf(vs * (1.f / 768.f) + LN_EPS);

    #pragma unroll
    for (int i = 0; i < 3; ++i) {
        const int cidx = tid + i * 256;
        out[(size_t)row * DD + cidx] = g[cidx] * (vals[i] - mu) * rstd + bta[cidx];
    }
}

// ---------------- launch -----------------------------------------------------
extern "C" void kernel_launch(void* const* d_in, const int* in_sizes, int n_in,
                              void* d_out, int out_size, void* d_ws, size_t ws_size,
                              hipStream_t stream) {
    const float* tgt   = (const float*)d_in[0];
    const float* qpos  = (const float*)d_in[1];
    const float* ploc  = (const float*)d_in[2];
    const float* Wq    = (const float*)d_in[3];
    const float* bq    = (const float*)d_in[4];
    const float* Wk    = (const float*)d_in[5];
    const float* bk    = (const float*)d_in[6];
    const float* Wv    = (const float*)d_in[7];
    const float* bv    = (const float*)d_in[8];
    const float* Wo    = (const float*)d_in[9];
    const float* bo    = (const float*)d_in[10];
    const float* Wloc  = (const float*)d_in[11];
    const float* bloc  = (const float*)d_in[12];
    const float* ln_g  = (const float*)d_in[13];
    const float* ln_b  = (const float*)d_in[14];

    const size_t NQ = (size_t)MM * DD;       // 6291456
    const size_t NW = (size_t)DD * DD;       // 589824
    short* qb   = (short*)d_ws;
    short* kb   = qb  + NQ;
    short* vtb  = kb  + NQ;
    short* aob  = vtb + NQ;
    short* aqk  = aob + NQ;
    short* av   = aqk + NQ;
    float* pbuf = (float*)aqk;               // reuse: aqk/av dead after GEMMs
    short* wqt  = av + NQ;
    short* wkt  = wqt + NW;
    short* wvt  = wkt + NW;
    short* wot  = wvt + NW;

    wtrans_kernel<<<dim3(12, 12, 4), 256, 0, stream>>>(Wq, Wk, Wv, Wo, wqt, wkt, wvt, wot);
    cast_inputs<<<3072, 256, 0, stream>>>(tgt, qpos, aqk, av);

    // Q + K fused: grid.x 0..5 -> Wq->qb, 6..11 -> Wk->kb  (768 blocks = 3/CU)
    gemm_mfma<1, true ><<<dim3(12, 64), 256, 0, stream>>>(aqk, wqt, bq, qb, wkt, bk, kb);
    gemm_mfma<2, false><<<dim3(6, 64),  256, 0, stream>>>(av,  wvt, bv, vtb, nullptr, nullptr, nullptr);

    attn_mfma<<<dim3(8, 12, 16), 256, 0, stream>>>(qb, kb, vtb, ploc, Wloc, bloc, aob);

    gemm_mfma<0, false><<<dim3(6, 64),  256, 0, stream>>>(aob, wot, bo, pbuf, nullptr, nullptr, nullptr);

    ln_kernel<<<MM, 256, 0, stream>>>(pbuf, tgt, ln_g, ln_b, (float*)d_out);
}

// Round 4
// 400.940 us; speedup vs baseline: 7.4588x; 1.0251x over previous
//
#include <hip/hip_runtime.h>
#include <math.h>

#define BB 16
#define LL 512
#define DD 768
#define HH 12
#define DHH 64
#define SPDD 5
#define MM (BB*LL)   // 8192
#define LN_EPS 1e-5f
#define CLAMP_MINV 1e-6f

typedef __attribute__((ext_vector_type(8))) short bf8_t;
typedef __attribute__((ext_vector_type(4))) float f4_t;

__device__ __forceinline__ short f2bf(float x) {
    unsigned u = __builtin_bit_cast(unsigned, x);
    unsigned r = (u + 0x7FFFu + ((u >> 16) & 1u)) >> 16;
    return (short)r;
}
__device__ __forceinline__ float bf2f(short s) {
    unsigned u = ((unsigned)(unsigned short)s) << 16;
    return __builtin_bit_cast(float, u);
}

__device__ __forceinline__ void gld16(const short* g, short* l) {
    __builtin_amdgcn_global_load_lds(
        (const __attribute__((address_space(1))) unsigned int*)g,
        (__attribute__((address_space(3))) unsigned int*)l,
        16, 0, 0);
}

// ---------------- block reduce (256 threads, wave64) ------------------------
__device__ __forceinline__ float block_sum(float v, float* red, int tid) {
    #pragma unroll
    for (int off = 32; off; off >>= 1) v += __shfl_down(v, off, 64);
    __syncthreads();
    if ((tid & 63) == 0) red[tid >> 6] = v;
    __syncthreads();
    return red[0] + red[1] + red[2] + red[3];
}

// ---------------- weight transpose + cast: Wt[n][k] = bf16(W[k][n]) ---------
__global__ __launch_bounds__(256) void wtrans_kernel(
    const float* __restrict__ W0, const float* __restrict__ W1,
    const float* __restrict__ W2, const float* __restrict__ W3,
    short* __restrict__ O0, short* __restrict__ O1,
    short* __restrict__ O2, short* __restrict__ O3)
{
    const float* W; short* O;
    switch (blockIdx.z) {
        case 0: W = W0; O = O0; break;
        case 1: W = W1; O = O1; break;
        case 2: W = W2; O = O2; break;
        default: W = W3; O = O3; break;
    }
    __shared__ float T[64][65];
    const int n0 = blockIdx.x * 64, k0 = blockIdx.y * 64;
    const int tid = threadIdx.x;
    {
        const int kk = tid >> 4, nv = (tid & 15) * 4;
        #pragma unroll
        for (int i = 0; i < 4; ++i) {
            const int k = kk + i * 16;
            const float4 v = *(const float4*)(W + (size_t)(k0 + k) * DD + n0 + nv);
            T[k][nv + 0] = v.x; T[k][nv + 1] = v.y;
            T[k][nv + 2] = v.z; T[k][nv + 3] = v.w;
        }
    }
    __syncthreads();
    {
        const int n = tid >> 2, kc = (tid & 3) * 16;
        short tmp[16];
        #pragma unroll
        for (int i = 0; i < 16; ++i) tmp[i] = f2bf(T[kc + i][n]);
        short* dst = O + (size_t)(n0 + n) * DD + k0 + kc;
        *(bf8_t*)dst       = *(bf8_t*)tmp;
        *(bf8_t*)(dst + 8) = *(bf8_t*)(tmp + 8);
    }
}

// ---------------- cast inputs: aqk = bf16(tgt+qpos), av = bf16(tgt) ---------
__global__ __launch_bounds__(256) void cast_inputs(
    const float* __restrict__ tgt, const float* __restrict__ qpos,
    short* __restrict__ aqk, short* __restrict__ av)
{
    const size_t base = ((size_t)blockIdx.x * 256 + threadIdx.x) * 8;
    const float4 t0 = *(const float4*)(tgt + base);
    const float4 t1 = *(const float4*)(tgt + base + 4);
    const float4 p0 = *(const float4*)(qpos + base);
    const float4 p1 = *(const float4*)(qpos + base + 4);
    short v[8], q[8];
    v[0] = f2bf(t0.x); v[1] = f2bf(t0.y); v[2] = f2bf(t0.z); v[3] = f2bf(t0.w);
    v[4] = f2bf(t1.x); v[5] = f2bf(t1.y); v[6] = f2bf(t1.z); v[7] = f2bf(t1.w);
    q[0] = f2bf(t0.x + p0.x); q[1] = f2bf(t0.y + p0.y);
    q[2] = f2bf(t0.z + p0.z); q[3] = f2bf(t0.w + p0.w);
    q[4] = f2bf(t1.x + p1.x); q[5] = f2bf(t1.y + p1.y);
    q[6] = f2bf(t1.z + p1.z); q[7] = f2bf(t1.w + p1.w);
    *(bf8_t*)(av + base)  = *(bf8_t*)v;
    *(bf8_t*)(aqk + base) = *(bf8_t*)q;
}

// ---------------- spatial log-bias precompute -------------------------------
// out[b][h][l][t] = bf16( log(clip(relu(ploc[b,l,t,:]·Wloc[:,h]+bloc[h]))) )
// thread handles 8 consecutive t for one (b,l), all 12 heads.
__global__ __launch_bounds__(256) void bias_kernel(
    const float* __restrict__ ploc, const float* __restrict__ Wloc,
    const float* __restrict__ bloc, short* __restrict__ out)
{
    const int g   = blockIdx.x * 256 + threadIdx.x;
    const int tch = g & 63;            // 64 chunks of 8 t
    const int l   = (g >> 6) & 511;
    const int b   = g >> 15;
    const int t0  = tch * 8;

    // 40 contiguous floats of ploc
    float p[40];
    const float* src = ploc + (((size_t)b * LL + l) * LL + t0) * SPDD;
    #pragma unroll
    for (int i = 0; i < 10; ++i)
        *(float4*)(p + i * 4) = *(const float4*)(src + i * 4);

    #pragma unroll
    for (int h = 0; h < HH; ++h) {
        float wl[SPDD];
        #pragma unroll
        for (int s = 0; s < SPDD; ++s) wl[s] = Wloc[s * HH + h];
        const float bl = bloc[h];
        short o[8];
        #pragma unroll
        for (int i = 0; i < 8; ++i) {
            float la = bl;
            #pragma unroll
            for (int s = 0; s < SPDD; ++s) la += p[i * SPDD + s] * wl[s];
            la = fmaxf(fmaxf(la, 0.f), CLAMP_MINV);
            o[i] = f2bf(__logf(la));
        }
        *(bf8_t*)(out + (((size_t)(b * HH + h) * LL + l) * LL + t0)) = *(bf8_t*)o;
    }
}

// ---------------- fused Q/K/V bf16 MFMA GEMM --------------------------------
// grid.x: 0..5 -> Q (aqk@WqT, BHLD), 6..11 -> K (aqk@WkT, BHLD),
//         12..17 -> V (av@WvT, BHDL).  Tile 128x128, BK=64, XOR-swizzled LDS.
__global__ __launch_bounds__(256) void gemm_qkv(
    const short* __restrict__ Aqk, const short* __restrict__ Av,
    const short* __restrict__ Wq, const float* __restrict__ bq, short* __restrict__ oq,
    const short* __restrict__ Wk, const float* __restrict__ bk, short* __restrict__ ok,
    const short* __restrict__ Wv, const float* __restrict__ bv, short* __restrict__ ov)
{
    __shared__ short As[128 * 64];
    __shared__ short Bs[128 * 64];
    const int seg = blockIdx.x / 6;
    const int bx = blockIdx.x % 6;
    const int by = blockIdx.y;
    const short* A  = (seg == 2) ? Av : Aqk;
    const short* Wt = (seg == 0) ? Wq : (seg == 1) ? Wk : Wv;
    const float* bias = (seg == 0) ? bq : (seg == 1) ? bk : bv;
    short* out = (seg == 0) ? oq : (seg == 1) ? ok : ov;

    const int n0 = bx * 128, m0 = by * 128;
    const int tid = threadIdx.x;
    const int w = tid >> 6, lane = tid & 63;
    const int quad = lane >> 4, l16 = lane & 15;
    const int wm = w & 1, wn = w >> 1;

    const int sr = w * 8 + (lane >> 3);
    const int sp = lane & 7;

    f4_t acc[4][4];
    #pragma unroll
    for (int i = 0; i < 4; ++i)
        #pragma unroll
        for (int j = 0; j < 4; ++j) acc[i][j] = (f4_t){0.f, 0.f, 0.f, 0.f};

    for (int k0 = 0; k0 < DD; k0 += 64) {
        __syncthreads();
        #pragma unroll
        for (int ra = 0; ra < 4; ++ra) {
            const int r = sr + ra * 32;
            const int c = sp ^ (r & 7);
            const int ldso = ra * 2048 + w * 512 + lane * 8;
            gld16(A  + (size_t)(m0 + r) * DD + k0 + c * 8, As + ldso);
            gld16(Wt + (size_t)(n0 + r) * DD + k0 + c * 8, Bs + ldso);
        }
        __syncthreads();
        #pragma unroll
        for (int s = 0; s < 2; ++s) {
            bf8_t a[4], b[4];
            #pragma unroll
            for (int i = 0; i < 4; ++i) {
                const int rA = wm * 64 + i * 16 + l16;
                const int pA = (s * 4 + quad) ^ (rA & 7);
                a[i] = *(const bf8_t*)(As + rA * 64 + pA * 8);
                const int rB = wn * 64 + i * 16 + l16;
                const int pB = (s * 4 + quad) ^ (rB & 7);
                b[i] = *(const bf8_t*)(Bs + rB * 64 + pB * 8);
            }
            #pragma unroll
            for (int i = 0; i < 4; ++i)
                #pragma unroll
                for (int j = 0; j < 4; ++j)
                    acc[i][j] = __builtin_amdgcn_mfma_f32_16x16x32_bf16(a[i], b[j], acc[i][j], 0, 0, 0);
        }
    }

    float bvv[4];
    #pragma unroll
    for (int j = 0; j < 4; ++j) bvv[j] = bias[n0 + wn * 64 + j * 16 + l16];
    #pragma unroll
    for (int i = 0; i < 4; ++i) {
        #pragma unroll
        for (int j = 0; j < 4; ++j) {
            const int n = n0 + wn * 64 + j * 16 + l16;
            #pragma unroll
            for (int r = 0; r < 4; ++r) {
                const int m = m0 + wm * 64 + i * 16 + quad * 4 + r;
                const float val = acc[i][j][r] + bvv[j];
                const int b_ = m >> 9, l = m & 511;
                const int h = n >> 6, d = n & 63;
                if (seg < 2)
                    out[(((size_t)(b_ * HH + h)) * LL + l) * DHH + d] = f2bf(val);
                else
                    out[(((size_t)(b_ * HH + h)) * DHH + d) * LL + l] = f2bf(val);
            }
        }
    }
}

// ---------------- O-projection GEMM: fp32 out flat --------------------------
__global__ __launch_bounds__(256) void gemm_o(
    const short* __restrict__ A, const short* __restrict__ Wt,
    const float* __restrict__ bias, float* __restrict__ out)
{
    __shared__ short As[128 * 64];
    __shared__ short Bs[128 * 64];
    const int bx = blockIdx.x, by = blockIdx.y;
    const int n0 = bx * 128, m0 = by * 128;
    const int tid = threadIdx.x;
    const int w = tid >> 6, lane = tid & 63;
    const int quad = lane >> 4, l16 = lane & 15;
    const int wm = w & 1, wn = w >> 1;
    const int sr = w * 8 + (lane >> 3);
    const int sp = lane & 7;

    f4_t acc[4][4];
    #pragma unroll
    for (int i = 0; i < 4; ++i)
        #pragma unroll
        for (int j = 0; j < 4; ++j) acc[i][j] = (f4_t){0.f, 0.f, 0.f, 0.f};

    for (int k0 = 0; k0 < DD; k0 += 64) {
        __syncthreads();
        #pragma unroll
        for (int ra = 0; ra < 4; ++ra) {
            const int r = sr + ra * 32;
            const int c = sp ^ (r & 7);
            const int ldso = ra * 2048 + w * 512 + lane * 8;
            gld16(A  + (size_t)(m0 + r) * DD + k0 + c * 8, As + ldso);
            gld16(Wt + (size_t)(n0 + r) * DD + k0 + c * 8, Bs + ldso);
        }
        __syncthreads();
        #pragma unroll
        for (int s = 0; s < 2; ++s) {
            bf8_t a[4], b[4];
            #pragma unroll
            for (int i = 0; i < 4; ++i) {
                const int rA = wm * 64 + i * 16 + l16;
                const int pA = (s * 4 + quad) ^ (rA & 7);
                a[i] = *(const bf8_t*)(As + rA * 64 + pA * 8);
                const int rB = wn * 64 + i * 16 + l16;
                const int pB = (s * 4 + quad) ^ (rB & 7);
                b[i] = *(const bf8_t*)(Bs + rB * 64 + pB * 8);
            }
            #pragma unroll
            for (int i = 0; i < 4; ++i)
                #pragma unroll
                for (int j = 0; j < 4; ++j)
                    acc[i][j] = __builtin_amdgcn_mfma_f32_16x16x32_bf16(a[i], b[j], acc[i][j], 0, 0, 0);
        }
    }

    float bvv[4];
    #pragma unroll
    for (int j = 0; j < 4; ++j) bvv[j] = bias[n0 + wn * 64 + j * 16 + l16];
    #pragma unroll
    for (int i = 0; i < 4; ++i)
        #pragma unroll
        for (int j = 0; j < 4; ++j) {
            const int n = n0 + wn * 64 + j * 16 + l16;
            #pragma unroll
            for (int r = 0; r < 4; ++r) {
                const int m = m0 + wm * 64 + i * 16 + quad * 4 + r;
                out[(size_t)m * DD + n] = acc[i][j][r] + bvv[j];
            }
        }
}

// ---------------- flash-style MFMA attention --------------------------------
// PRE=true: logbias precomputed bf16 [B,H,L,L].  PRE=false: compute from ploc.
// XOR swizzle (16B chunks, ^(row&7)) on Ks/Vs/Ps; bias tile bf16 stride 68.
template<bool PRE>
__global__ __launch_bounds__(256) void attn_mfma(
    const short* __restrict__ Q, const short* __restrict__ K,
    const short* __restrict__ Vt, const short* __restrict__ LB,
    const float* __restrict__ ploc, const float* __restrict__ Wloc,
    const float* __restrict__ bloc, short* __restrict__ out)
{
    __shared__ short Ks[64 * 64];
    __shared__ short Vs[64 * 64];
    __shared__ short bs16[64 * 68];
    __shared__ short Ps[4][16 * 64];

    const int qt = blockIdx.x, h = blockIdx.y, b = blockIdx.z;
    const int tid = threadIdx.x;
    const int w = tid >> 6, lane = tid & 63;
    const int quad = lane >> 4, l16 = lane & 15;
    const int q0 = qt * 64;
    const size_t bh = (size_t)b * HH + h;

    float wl[SPDD];
    float blc = 0.f;
    if (!PRE) {
        #pragma unroll
        for (int s = 0; s < SPDD; ++s) wl[s] = Wloc[s * HH + h];
        blc = bloc[h];
    }

    const int qr = q0 + w * 16 + l16;
    const bf8_t aq0 = *(const bf8_t*)(Q + (bh * LL + qr) * DHH + quad * 8);
    const bf8_t aq1 = *(const bf8_t*)(Q + (bh * LL + qr) * DHH + quad * 8 + 32);

    f4_t o[4];
    #pragma unroll
    for (int dj = 0; dj < 4; ++dj) o[dj] = (f4_t){0.f, 0.f, 0.f, 0.f};
    float m_row[4], l_row[4];
    #pragma unroll
    for (int r = 0; r < 4; ++r) { m_row[r] = -1e30f; l_row[r] = 0.f; }

    const short* Kg = K  + bh * LL * DHH;
    const short* Vg = Vt + bh * DHH * LL;
    const short* Bg = PRE ? (LB + (bh * LL + q0) * LL) : nullptr;

    const int srow = tid >> 2;              // staging row 0..63
    const int cb   = (tid & 3) * 2;         // first of two 16B chunks
    const int sw   = srow & 7;

    for (int t0 = 0; t0 < LL; t0 += 64) {
        __syncthreads();
        // ---- stage K tile (swizzled) ----
        {
            const short* src = Kg + (size_t)(t0 + srow) * DHH + cb * 8;
            *(bf8_t*)(Ks + srow * 64 + ((cb ^ sw) * 8))       = *(const bf8_t*)(src);
            *(bf8_t*)(Ks + srow * 64 + (((cb + 1) ^ sw) * 8)) = *(const bf8_t*)(src + 8);
        }
        // ---- stage V^T tile (swizzled) ----
        {
            const short* src = Vg + (size_t)srow * LL + t0 + cb * 8;
            *(bf8_t*)(Vs + srow * 64 + ((cb ^ sw) * 8))       = *(const bf8_t*)(src);
            *(bf8_t*)(Vs + srow * 64 + (((cb + 1) ^ sw) * 8)) = *(const bf8_t*)(src + 8);
        }
        // ---- stage bias tile ----
        {
            const int l = tid >> 2, ts = (tid & 3) * 16;
            if (PRE) {
                const short* src = Bg + (size_t)l * LL + t0 + ts;
                #pragma unroll
                for (int i = 0; i < 4; ++i)
                    *(short4*)(bs16 + l * 68 + ts + i * 4) = *(const short4*)(src + i * 4);
            } else {
                const float* pp = ploc + (((size_t)b * LL + q0 + l) * LL + t0 + ts) * SPDD;
                #pragma unroll
                for (int i = 0; i < 16; ++i) {
                    float la = blc;
                    #pragma unroll
                    for (int s = 0; s < SPDD; ++s) la += pp[i * SPDD + s] * wl[s];
                    la = fmaxf(fmaxf(la, 0.f), CLAMP_MINV);
                    bs16[l * 68 + ts + i] = f2bf(__logf(la));
                }
            }
        }
        __syncthreads();

        // ---- S = Q K^T ----
        f4_t sv[4];
        #pragma unroll
        for (int j = 0; j < 4; ++j) {
            const int rB = j * 16 + l16;
            const int x = rB & 7;
            const bf8_t b0 = *(const bf8_t*)(Ks + rB * 64 + ((quad ^ x) * 8));
            const bf8_t b1 = *(const bf8_t*)(Ks + rB * 64 + (((quad + 4) ^ x) * 8));
            f4_t c = (f4_t){0.f, 0.f, 0.f, 0.f};
            c = __builtin_amdgcn_mfma_f32_16x16x32_bf16(aq0, b0, c, 0, 0, 0);
            c = __builtin_amdgcn_mfma_f32_16x16x32_bf16(aq1, b1, c, 0, 0, 0);
            sv[j] = c;
        }
        // ---- scale + bias ----
        #pragma unroll
        for (int j = 0; j < 4; ++j)
            #pragma unroll
            for (int r = 0; r < 4; ++r) {
                const int lrel = w * 16 + quad * 4 + r;
                sv[j][r] = sv[j][r] * 0.125f + bf2f(bs16[lrel * 68 + j * 16 + l16]);
            }
        // ---- online softmax ----
        #pragma unroll
        for (int r = 0; r < 4; ++r) {
            float mx = fmaxf(fmaxf(sv[0][r], sv[1][r]), fmaxf(sv[2][r], sv[3][r]));
            mx = fmaxf(mx, __shfl_xor(mx, 1, 16));
            mx = fmaxf(mx, __shfl_xor(mx, 2, 16));
            mx = fmaxf(mx, __shfl_xor(mx, 4, 16));
            mx = fmaxf(mx, __shfl_xor(mx, 8, 16));
            const float mn = fmaxf(m_row[r], mx);
            const float al = __expf(m_row[r] - mn);
            m_row[r] = mn;
            float rs = 0.f;
            #pragma unroll
            for (int j = 0; j < 4; ++j) {
                const float p = __expf(sv[j][r] - mn);
                sv[j][r] = p;
                rs += p;
            }
            rs += __shfl_xor(rs, 1, 16);
            rs += __shfl_xor(rs, 2, 16);
            rs += __shfl_xor(rs, 4, 16);
            rs += __shfl_xor(rs, 8, 16);
            l_row[r] = l_row[r] * al + rs;
            #pragma unroll
            for (int dj = 0; dj < 4; ++dj) o[dj][r] *= al;
        }
        // ---- P: C-layout -> swizzled LDS -> A-layout ----
        short* Pw = Ps[w];
        #pragma unroll
        for (int r = 0; r < 4; ++r) {
            const int rp = quad * 4 + r, rp7 = rp & 7;
            #pragma unroll
            for (int j = 0; j < 4; ++j) {
                const int t = j * 16 + l16;
                Pw[rp * 64 + (((t >> 3) ^ rp7) * 8) + (t & 7)] = f2bf(sv[j][r]);
            }
        }
        const int m7 = l16 & 7;
        const bf8_t ap0 = *(const bf8_t*)(Pw + l16 * 64 + ((quad ^ m7) * 8));
        const bf8_t ap1 = *(const bf8_t*)(Pw + l16 * 64 + (((quad + 4) ^ m7) * 8));
        #pragma unroll
        for (int dj = 0; dj < 4; ++dj) {
            const int rB = dj * 16 + l16;
            const int x = rB & 7;
            const bf8_t b0 = *(const bf8_t*)(Vs + rB * 64 + ((quad ^ x) * 8));
            const bf8_t b1 = *(const bf8_t*)(Vs + rB * 64 + (((quad + 4) ^ x) * 8));
            o[dj] = __builtin_amdgcn_mfma_f32_16x16x32_bf16(ap0, b0, o[dj], 0, 0, 0);
            o[dj] = __builtin_amdgcn_mfma_f32_16x16x32_bf16(ap1, b1, o[dj], 0, 0, 0);
        }
    }

    #pragma unroll
    for (int r = 0; r < 4; ++r) {
        const int l = q0 + w * 16 + quad * 4 + r;
        const float inv = 1.f / l_row[r];
        short* op = out + ((size_t)b * LL + l) * DD + h * DHH;
        #pragma unroll
        for (int dj = 0; dj < 4; ++dj)
            op[dj * 16 + l16] = f2bf(o[dj][r] * inv);
    }
}

// ---------------- residual + LayerNorm --------------------------------------
__global__ __launch_bounds__(256) void ln_kernel(
    const float* __restrict__ x, const float* __restrict__ tgt,
    const float* __restrict__ g, const float* __restrict__ bta,
    float* __restrict__ out)
{
    const int row = blockIdx.x;
    const int tid = threadIdx.x;
    __shared__ float red[4];

    const float* xp = x + (size_t)row * DD;
    const float* tp = tgt + (size_t)row * DD;

    float vals[3];
    float s = 0.f;
    #pragma unroll
    for (int i = 0; i < 3; ++i) {
        const float v = xp[tid + i * 256] + tp[tid + i * 256];
        vals[i] = v;
        s += v;
    }
    s = block_sum(s, red, tid);
    const float mu = s * (1.f / 768.f);

    float vs = 0.f;
    #pragma unroll
    for (int i = 0; i < 3; ++i) {
        const float dv = vals[i] - mu;
        vs += dv * dv;
    }
    vs = block_sum(vs, red, tid);
    const float rstd = rsqrtf(vs * (1.f / 768.f) + LN_EPS);

    #pragma unroll
    for (int i = 0; i < 3; ++i) {
        const int cidx = tid + i * 256;
        out[(size_t)row * DD + cidx] = g[cidx] * (vals[i] - mu) * rstd + bta[cidx];
    }
}

// ---------------- launch -----------------------------------------------------
extern "C" void kernel_launch(void* const* d_in, const int* in_sizes, int n_in,
                              void* d_out, int out_size, void* d_ws, size_t ws_size,
                              hipStream_t stream) {
    const float* tgt   = (const float*)d_in[0];
    const float* qpos  = (const float*)d_in[1];
    const float* ploc  = (const float*)d_in[2];
    const float* Wq    = (const float*)d_in[3];
    const float* bq    = (const float*)d_in[4];
    const float* Wk    = (const float*)d_in[5];
    const float* bk    = (const float*)d_in[6];
    const float* Wv    = (const float*)d_in[7];
    const float* bv    = (const float*)d_in[8];
    const float* Wo    = (const float*)d_in[9];
    const float* bo    = (const float*)d_in[10];
    const float* Wloc  = (const float*)d_in[11];
    const float* bloc  = (const float*)d_in[12];
    const float* ln_g  = (const float*)d_in[13];
    const float* ln_b  = (const float*)d_in[14];

    const size_t NQ = (size_t)MM * DD;           // 6291456
    const size_t NW = (size_t)DD * DD;           // 589824
    const size_t NB = (size_t)BB * HH * LL * LL; // 50331648

    short* qb   = (short*)d_ws;
    short* kb   = qb  + NQ;
    short* vtb  = kb  + NQ;
    short* aob  = vtb + NQ;
    short* aqk  = aob + NQ;
    short* av   = aqk + NQ;
    float* pbuf = (float*)aqk;                   // alias (aqk,av dead by then)
    short* wqt  = av + NQ;
    short* wkt  = wqt + NW;
    short* wvt  = wkt + NW;
    short* wot  = wvt + NW;
    short* lb   = wot + NW;

    const size_t needed = (size_t)(6 * NQ + 4 * NW + NB) * 2;
    const bool pre = (ws_size >= needed);

    wtrans_kernel<<<dim3(12, 12, 4), 256, 0, stream>>>(Wq, Wk, Wv, Wo, wqt, wkt, wvt, wot);
    cast_inputs<<<3072, 256, 0, stream>>>(tgt, qpos, aqk, av);
    if (pre)
        bias_kernel<<<2048, 256, 0, stream>>>(ploc, Wloc, bloc, lb);

    gemm_qkv<<<dim3(18, 64), 256, 0, stream>>>(aqk, av, wqt, bq, qb,
                                               wkt, bk, kb, wvt, bv, vtb);

    if (pre)
        attn_mfma<true ><<<dim3(8, 12, 16), 256, 0, stream>>>(qb, kb, vtb, lb, ploc, Wloc, bloc, aob);
    else
        attn_mfma<false><<<dim3(8, 12, 16), 256, 0, stream>>>(qb, kb, vtb, nullptr, ploc, Wloc, bloc, aob);

    gemm_o<<<dim3(6, 64), 256, 0, stream>>>(aob, wot, bo, pbuf);

    ln_kernel<<<MM, 256, 0, stream>>>(pbuf, tgt, ln_g, ln_b, (float*)d_out);
}

// Round 5
// 368.360 us; speedup vs baseline: 8.1185x; 1.0884x over previous
//
#include <hip/hip_runtime.h>
#include <math.h>

#define BB 16
#define LL 512
#define DD 768
#define HH 12
#define DHH 64
#define SPDD 5
#define MM (BB*LL)   // 8192
#define LN_EPS 1e-5f
#define CLAMP_MINV 1e-6f

typedef __attribute__((ext_vector_type(8))) short bf8_t;
typedef __attribute__((ext_vector_type(4))) float f4_t;

__device__ __forceinline__ short f2bf(float x) {
    unsigned u = __builtin_bit_cast(unsigned, x);
    unsigned r = (u + 0x7FFFu + ((u >> 16) & 1u)) >> 16;
    return (short)r;
}
__device__ __forceinline__ float bf2f(short s) {
    unsigned u = ((unsigned)(unsigned short)s) << 16;
    return __builtin_bit_cast(float, u);
}

__device__ __forceinline__ void gld16(const short* g, short* l) {
    __builtin_amdgcn_global_load_lds(
        (const __attribute__((address_space(1))) unsigned int*)g,
        (__attribute__((address_space(3))) unsigned int*)l,
        16, 0, 0);
}

// ---------------- block reduce (256 threads, wave64) ------------------------
__device__ __forceinline__ float block_sum(float v, float* red, int tid) {
    #pragma unroll
    for (int off = 32; off; off >>= 1) v += __shfl_down(v, off, 64);
    __syncthreads();
    if ((tid & 63) == 0) red[tid >> 6] = v;
    __syncthreads();
    return red[0] + red[1] + red[2] + red[3];
}

// ---------------- fused prep: la-bias + input cast + weight transpose -------
// blocks [0,2048): la[b][h][l][t] = bf16(clip(relu(ploc·Wloc+bloc)))
// blocks [2048,5120): aqk = bf16(tgt+qpos), av = bf16(tgt)
// blocks [5120,5696): Wt[n][k] = bf16(W[k][n]) for 4 weights
template<bool PRE>
__global__ __launch_bounds__(256) void prep_kernel(
    const float* __restrict__ tgt, const float* __restrict__ qpos,
    const float* __restrict__ ploc, const float* __restrict__ Wloc,
    const float* __restrict__ bloc,
    const float* __restrict__ W0, const float* __restrict__ W1,
    const float* __restrict__ W2, const float* __restrict__ W3,
    short* __restrict__ aqk, short* __restrict__ av, short* __restrict__ la,
    short* __restrict__ O0, short* __restrict__ O1,
    short* __restrict__ O2, short* __restrict__ O3)
{
    __shared__ float T[64][65];
    const int nbias = PRE ? 2048 : 0;
    const int t = blockIdx.x;
    if (PRE && t < nbias) {
        // ---- spatial la precompute ----
        const int g   = t * 256 + threadIdx.x;
        const int tch = g & 63;
        const int l   = (g >> 6) & 511;
        const int b   = g >> 15;
        const int t0  = tch * 8;
        float p[40];
        const float* src = ploc + (((size_t)b * LL + l) * LL + t0) * SPDD;
        #pragma unroll
        for (int i = 0; i < 10; ++i)
            *(float4*)(p + i * 4) = *(const float4*)(src + i * 4);
        #pragma unroll
        for (int h = 0; h < HH; ++h) {
            float wl[SPDD];
            #pragma unroll
            for (int s = 0; s < SPDD; ++s) wl[s] = Wloc[s * HH + h];
            const float bl = bloc[h];
            short o[8];
            #pragma unroll
            for (int i = 0; i < 8; ++i) {
                float v = bl;
                #pragma unroll
                for (int s = 0; s < SPDD; ++s) v += p[i * SPDD + s] * wl[s];
                v = fmaxf(fmaxf(v, 0.f), CLAMP_MINV);
                o[i] = f2bf(v);
            }
            *(bf8_t*)(la + (((size_t)(b * HH + h) * LL + l) * LL + t0)) = *(bf8_t*)o;
        }
    } else if (t < nbias + 3072) {
        // ---- input cast ----
        const int cb = t - nbias;
        const size_t base = ((size_t)cb * 256 + threadIdx.x) * 8;
        const float4 t0 = *(const float4*)(tgt + base);
        const float4 t1 = *(const float4*)(tgt + base + 4);
        const float4 p0 = *(const float4*)(qpos + base);
        const float4 p1 = *(const float4*)(qpos + base + 4);
        short v[8], q[8];
        v[0] = f2bf(t0.x); v[1] = f2bf(t0.y); v[2] = f2bf(t0.z); v[3] = f2bf(t0.w);
        v[4] = f2bf(t1.x); v[5] = f2bf(t1.y); v[6] = f2bf(t1.z); v[7] = f2bf(t1.w);
        q[0] = f2bf(t0.x + p0.x); q[1] = f2bf(t0.y + p0.y);
        q[2] = f2bf(t0.z + p0.z); q[3] = f2bf(t0.w + p0.w);
        q[4] = f2bf(t1.x + p1.x); q[5] = f2bf(t1.y + p1.y);
        q[6] = f2bf(t1.z + p1.z); q[7] = f2bf(t1.w + p1.w);
        *(bf8_t*)(av + base)  = *(bf8_t*)v;
        *(bf8_t*)(aqk + base) = *(bf8_t*)q;
    } else {
        // ---- weight transpose + cast ----
        const int wt = t - (nbias + 3072);      // 0..575
        const int wi = wt / 144;
        const int rem = wt % 144;
        const float* W; short* O;
        switch (wi) {
            case 0: W = W0; O = O0; break;
            case 1: W = W1; O = O1; break;
            case 2: W = W2; O = O2; break;
            default: W = W3; O = O3; break;
        }
        const int n0 = (rem % 12) * 64, k0 = (rem / 12) * 64;
        const int tid = threadIdx.x;
        {
            const int kk = tid >> 4, nv = (tid & 15) * 4;
            #pragma unroll
            for (int i = 0; i < 4; ++i) {
                const int k = kk + i * 16;
                const float4 v = *(const float4*)(W + (size_t)(k0 + k) * DD + n0 + nv);
                T[k][nv + 0] = v.x; T[k][nv + 1] = v.y;
                T[k][nv + 2] = v.z; T[k][nv + 3] = v.w;
            }
        }
        __syncthreads();
        {
            const int n = tid >> 2, kc = (tid & 3) * 16;
            short tmp[16];
            #pragma unroll
            for (int i = 0; i < 16; ++i) tmp[i] = f2bf(T[kc + i][n]);
            short* dst = O + (size_t)(n0 + n) * DD + k0 + kc;
            *(bf8_t*)dst       = *(bf8_t*)tmp;
            *(bf8_t*)(dst + 8) = *(bf8_t*)(tmp + 8);
        }
    }
}

// ---------------- fused Q/K/V bf16 MFMA GEMM (XCD-swizzled) -----------------
__global__ __launch_bounds__(256) void gemm_qkv(
    const short* __restrict__ Aqk, const short* __restrict__ Av,
    const short* __restrict__ Wq, const float* __restrict__ bq, short* __restrict__ oq,
    const short* __restrict__ Wk, const float* __restrict__ bk, short* __restrict__ ok,
    const short* __restrict__ Wv, const float* __restrict__ bv, short* __restrict__ ov)
{
    __shared__ short As[128 * 64];
    __shared__ short Bs[128 * 64];
    // XCD remap: id%8 = XCD (round-robin); give each XCD 8 contiguous m-blocks
    const int id = blockIdx.y * 18 + blockIdx.x;
    const int xcd = id & 7, j = id >> 3;          // j: 0..143
    const int by = xcd * 8 + j / 18;
    const int gx = j % 18;
    const int seg = gx / 6;
    const int bx = gx % 6;
    const short* A  = (seg == 2) ? Av : Aqk;
    const short* Wt = (seg == 0) ? Wq : (seg == 1) ? Wk : Wv;
    const float* bias = (seg == 0) ? bq : (seg == 1) ? bk : bv;
    short* out = (seg == 0) ? oq : (seg == 1) ? ok : ov;

    const int n0 = bx * 128, m0 = by * 128;
    const int tid = threadIdx.x;
    const int w = tid >> 6, lane = tid & 63;
    const int quad = lane >> 4, l16 = lane & 15;
    const int wm = w & 1, wn = w >> 1;
    const int sr = w * 8 + (lane >> 3);
    const int sp = lane & 7;

    f4_t acc[4][4];
    #pragma unroll
    for (int i = 0; i < 4; ++i)
        #pragma unroll
        for (int jj = 0; jj < 4; ++jj) acc[i][jj] = (f4_t){0.f, 0.f, 0.f, 0.f};

    for (int k0 = 0; k0 < DD; k0 += 64) {
        __syncthreads();
        #pragma unroll
        for (int ra = 0; ra < 4; ++ra) {
            const int r = sr + ra * 32;
            const int c = sp ^ (r & 7);
            const int ldso = ra * 2048 + w * 512 + lane * 8;
            gld16(A  + (size_t)(m0 + r) * DD + k0 + c * 8, As + ldso);
            gld16(Wt + (size_t)(n0 + r) * DD + k0 + c * 8, Bs + ldso);
        }
        __syncthreads();
        #pragma unroll
        for (int s = 0; s < 2; ++s) {
            bf8_t a[4], b[4];
            #pragma unroll
            for (int i = 0; i < 4; ++i) {
                const int rA = wm * 64 + i * 16 + l16;
                const int pA = (s * 4 + quad) ^ (rA & 7);
                a[i] = *(const bf8_t*)(As + rA * 64 + pA * 8);
                const int rB = wn * 64 + i * 16 + l16;
                const int pB = (s * 4 + quad) ^ (rB & 7);
                b[i] = *(const bf8_t*)(Bs + rB * 64 + pB * 8);
            }
            #pragma unroll
            for (int i = 0; i < 4; ++i)
                #pragma unroll
                for (int jj = 0; jj < 4; ++jj)
                    acc[i][jj] = __builtin_amdgcn_mfma_f32_16x16x32_bf16(a[i], b[jj], acc[i][jj], 0, 0, 0);
        }
    }

    float bvv[4];
    #pragma unroll
    for (int jj = 0; jj < 4; ++jj) bvv[jj] = bias[n0 + wn * 64 + jj * 16 + l16];
    #pragma unroll
    for (int i = 0; i < 4; ++i) {
        #pragma unroll
        for (int jj = 0; jj < 4; ++jj) {
            const int n = n0 + wn * 64 + jj * 16 + l16;
            #pragma unroll
            for (int r = 0; r < 4; ++r) {
                const int m = m0 + wm * 64 + i * 16 + quad * 4 + r;
                const float val = acc[i][jj][r] + bvv[jj];
                const int b_ = m >> 9, l = m & 511;
                const int h = n >> 6, d = n & 63;
                if (seg < 2)
                    out[(((size_t)(b_ * HH + h)) * LL + l) * DHH + d] = f2bf(val);
                else
                    out[(((size_t)(b_ * HH + h)) * DHH + d) * LL + l] = f2bf(val);
            }
        }
    }
}

// ---------------- O-projection GEMM (XCD-swizzled, fp32 out) ----------------
__global__ __launch_bounds__(256) void gemm_o(
    const short* __restrict__ A, const short* __restrict__ Wt,
    const float* __restrict__ bias, float* __restrict__ out)
{
    __shared__ short As[128 * 64];
    __shared__ short Bs[128 * 64];
    const int id = blockIdx.y * 6 + blockIdx.x;
    const int xcd = id & 7, j = id >> 3;          // j: 0..47
    const int by = xcd * 8 + j / 6;
    const int bx = j % 6;
    const int n0 = bx * 128, m0 = by * 128;
    const int tid = threadIdx.x;
    const int w = tid >> 6, lane = tid & 63;
    const int quad = lane >> 4, l16 = lane & 15;
    const int wm = w & 1, wn = w >> 1;
    const int sr = w * 8 + (lane >> 3);
    const int sp = lane & 7;

    f4_t acc[4][4];
    #pragma unroll
    for (int i = 0; i < 4; ++i)
        #pragma unroll
        for (int jj = 0; jj < 4; ++jj) acc[i][jj] = (f4_t){0.f, 0.f, 0.f, 0.f};

    for (int k0 = 0; k0 < DD; k0 += 64) {
        __syncthreads();
        #pragma unroll
        for (int ra = 0; ra < 4; ++ra) {
            const int r = sr + ra * 32;
            const int c = sp ^ (r & 7);
            const int ldso = ra * 2048 + w * 512 + lane * 8;
            gld16(A  + (size_t)(m0 + r) * DD + k0 + c * 8, As + ldso);
            gld16(Wt + (size_t)(n0 + r) * DD + k0 + c * 8, Bs + ldso);
        }
        __syncthreads();
        #pragma unroll
        for (int s = 0; s < 2; ++s) {
            bf8_t a[4], b[4];
            #pragma unroll
            for (int i = 0; i < 4; ++i) {
                const int rA = wm * 64 + i * 16 + l16;
                const int pA = (s * 4 + quad) ^ (rA & 7);
                a[i] = *(const bf8_t*)(As + rA * 64 + pA * 8);
                const int rB = wn * 64 + i * 16 + l16;
                const int pB = (s * 4 + quad) ^ (rB & 7);
                b[i] = *(const bf8_t*)(Bs + rB * 64 + pB * 8);
            }
            #pragma unroll
            for (int i = 0; i < 4; ++i)
                #pragma unroll
                for (int jj = 0; jj < 4; ++jj)
                    acc[i][jj] = __builtin_amdgcn_mfma_f32_16x16x32_bf16(a[i], b[jj], acc[i][jj], 0, 0, 0);
        }
    }

    float bvv[4];
    #pragma unroll
    for (int jj = 0; jj < 4; ++jj) bvv[jj] = bias[n0 + wn * 64 + jj * 16 + l16];
    #pragma unroll
    for (int i = 0; i < 4; ++i)
        #pragma unroll
        for (int jj = 0; jj < 4; ++jj) {
            const int n = n0 + wn * 64 + jj * 16 + l16;
            #pragma unroll
            for (int r = 0; r < 4; ++r) {
                const int m = m0 + wm * 64 + i * 16 + quad * 4 + r;
                out[(size_t)m * DD + n] = acc[i][jj][r] + bvv[jj];
            }
        }
}

// ---------------- flash-style MFMA attention --------------------------------
// grid (192, 8): x = h + 12*b, y = qt  (qt slowest -> same-(b,h) blocks on one XCD)
// p = la * exp(s - m): softmax(log la + s) without the log.
template<bool PRE>
__global__ __launch_bounds__(256) void attn_mfma(
    const short* __restrict__ Q, const short* __restrict__ K,
    const short* __restrict__ Vt, const short* __restrict__ LA,
    const float* __restrict__ ploc, const float* __restrict__ Wloc,
    const float* __restrict__ bloc, short* __restrict__ out)
{
    __shared__ short Ks[64 * 64];
    __shared__ short Vs[64 * 64];
    __shared__ short bs16[64 * 68];
    __shared__ short Ps[4][16 * 64];

    const int h = blockIdx.x % 12, b = blockIdx.x / 12;
    const int qt = blockIdx.y;
    const int tid = threadIdx.x;
    const int w = tid >> 6, lane = tid & 63;
    const int quad = lane >> 4, l16 = lane & 15;
    const int q0 = qt * 64;
    const size_t bh = (size_t)b * HH + h;

    float wl[SPDD];
    float blc = 0.f;
    if (!PRE) {
        #pragma unroll
        for (int s = 0; s < SPDD; ++s) wl[s] = Wloc[s * HH + h];
        blc = bloc[h];
    }

    const int qr = q0 + w * 16 + l16;
    const bf8_t aq0 = *(const bf8_t*)(Q + (bh * LL + qr) * DHH + quad * 8);
    const bf8_t aq1 = *(const bf8_t*)(Q + (bh * LL + qr) * DHH + quad * 8 + 32);

    f4_t o[4];
    #pragma unroll
    for (int dj = 0; dj < 4; ++dj) o[dj] = (f4_t){0.f, 0.f, 0.f, 0.f};
    float m_row[4], l_row[4];
    #pragma unroll
    for (int r = 0; r < 4; ++r) { m_row[r] = -1e30f; l_row[r] = 0.f; }

    const short* Kg = K  + bh * LL * DHH;
    const short* Vg = Vt + bh * DHH * LL;
    const short* Bg = PRE ? (LA + (bh * LL + q0) * LL) : nullptr;

    const int srow = tid >> 2;
    const int cb   = (tid & 3) * 2;
    const int sw   = srow & 7;

    for (int t0 = 0; t0 < LL; t0 += 64) {
        __syncthreads();
        {
            const short* src = Kg + (size_t)(t0 + srow) * DHH + cb * 8;
            *(bf8_t*)(Ks + srow * 64 + ((cb ^ sw) * 8))       = *(const bf8_t*)(src);
            *(bf8_t*)(Ks + srow * 64 + (((cb + 1) ^ sw) * 8)) = *(const bf8_t*)(src + 8);
        }
        {
            const short* src = Vg + (size_t)srow * LL + t0 + cb * 8;
            *(bf8_t*)(Vs + srow * 64 + ((cb ^ sw) * 8))       = *(const bf8_t*)(src);
            *(bf8_t*)(Vs + srow * 64 + (((cb + 1) ^ sw) * 8)) = *(const bf8_t*)(src + 8);
        }
        {
            const int l = tid >> 2, ts = (tid & 3) * 16;
            if (PRE) {
                const short* src = Bg + (size_t)l * LL + t0 + ts;
                #pragma unroll
                for (int i = 0; i < 4; ++i)
                    *(short4*)(bs16 + l * 68 + ts + i * 4) = *(const short4*)(src + i * 4);
            } else {
                const float* pp = ploc + (((size_t)b * LL + q0 + l) * LL + t0 + ts) * SPDD;
                #pragma unroll
                for (int i = 0; i < 16; ++i) {
                    float v = blc;
                    #pragma unroll
                    for (int s = 0; s < SPDD; ++s) v += pp[i * SPDD + s] * wl[s];
                    v = fmaxf(fmaxf(v, 0.f), CLAMP_MINV);
                    bs16[l * 68 + ts + i] = f2bf(v);
                }
            }
        }
        __syncthreads();

        // ---- S = Q K^T ----
        f4_t sv[4];
        #pragma unroll
        for (int j = 0; j < 4; ++j) {
            const int rB = j * 16 + l16;
            const int x = rB & 7;
            const bf8_t b0 = *(const bf8_t*)(Ks + rB * 64 + ((quad ^ x) * 8));
            const bf8_t b1 = *(const bf8_t*)(Ks + rB * 64 + (((quad + 4) ^ x) * 8));
            f4_t c = (f4_t){0.f, 0.f, 0.f, 0.f};
            c = __builtin_amdgcn_mfma_f32_16x16x32_bf16(aq0, b0, c, 0, 0, 0);
            c = __builtin_amdgcn_mfma_f32_16x16x32_bf16(aq1, b1, c, 0, 0, 0);
            sv[j] = c;
        }
        #pragma unroll
        for (int j = 0; j < 4; ++j)
            #pragma unroll
            for (int r = 0; r < 4; ++r) sv[j][r] *= 0.125f;

        // ---- online softmax: p = la * exp(s - m), m tracked over s only ----
        #pragma unroll
        for (int r = 0; r < 4; ++r) {
            const int lrel = w * 16 + quad * 4 + r;
            float mx = fmaxf(fmaxf(sv[0][r], sv[1][r]), fmaxf(sv[2][r], sv[3][r]));
            mx = fmaxf(mx, __shfl_xor(mx, 1, 16));
            mx = fmaxf(mx, __shfl_xor(mx, 2, 16));
            mx = fmaxf(mx, __shfl_xor(mx, 4, 16));
            mx = fmaxf(mx, __shfl_xor(mx, 8, 16));
            const float mn = fmaxf(m_row[r], mx);
            const float al = __expf(m_row[r] - mn);
            m_row[r] = mn;
            float rs = 0.f;
            #pragma unroll
            for (int j = 0; j < 4; ++j) {
                const float lav = bf2f(bs16[lrel * 68 + j * 16 + l16]);
                const float p = lav * __expf(sv[j][r] - mn);
                sv[j][r] = p;
                rs += p;
            }
            rs += __shfl_xor(rs, 1, 16);
            rs += __shfl_xor(rs, 2, 16);
            rs += __shfl_xor(rs, 4, 16);
            rs += __shfl_xor(rs, 8, 16);
            l_row[r] = l_row[r] * al + rs;
            #pragma unroll
            for (int dj = 0; dj < 4; ++dj) o[dj][r] *= al;
        }
        // ---- P: C-layout -> swizzled LDS -> A-layout ----
        short* Pw = Ps[w];
        #pragma unroll
        for (int r = 0; r < 4; ++r) {
            const int rp = quad * 4 + r, rp7 = rp & 7;
            #pragma unroll
            for (int j = 0; j < 4; ++j) {
                const int t = j * 16 + l16;
                Pw[rp * 64 + (((t >> 3) ^ rp7) * 8) + (t & 7)] = f2bf(sv[j][r]);
            }
        }
        const int m7 = l16 & 7;
        const bf8_t ap0 = *(const bf8_t*)(Pw + l16 * 64 + ((quad ^ m7) * 8));
        const bf8_t ap1 = *(const bf8_t*)(Pw + l16 * 64 + (((quad + 4) ^ m7) * 8));
        #pragma unroll
        for (int dj = 0; dj < 4; ++dj) {
            const int rB = dj * 16 + l16;
            const int x = rB & 7;
            const bf8_t b0 = *(const bf8_t*)(Vs + rB * 64 + ((quad ^ x) * 8));
            const bf8_t b1 = *(const bf8_t*)(Vs + rB * 64 + (((quad + 4) ^ x) * 8));
            o[dj] = __builtin_amdgcn_mfma_f32_16x16x32_bf16(ap0, b0, o[dj], 0, 0, 0);
            o[dj] = __builtin_amdgcn_mfma_f32_16x16x32_bf16(ap1, b1, o[dj], 0, 0, 0);
        }
    }

    #pragma unroll
    for (int r = 0; r < 4; ++r) {
        const int l = q0 + w * 16 + quad * 4 + r;
        const float inv = 1.f / l_row[r];
        short* op = out + ((size_t)b * LL + l) * DD + h * DHH;
        #pragma unroll
        for (int dj = 0; dj < 4; ++dj)
            op[dj * 16 + l16] = f2bf(o[dj][r] * inv);
    }
}

// ---------------- residual + LayerNorm --------------------------------------
__global__ __launch_bounds__(256) void ln_kernel(
    const float* __restrict__ x, const float* __restrict__ tgt,
    const float* __restrict__ g, const float* __restrict__ bta,
    float* __restrict__ out)
{
    const int row = blockIdx.x;
    const int tid = threadIdx.x;
    __shared__ float red[4];

    const float* xp = x + (size_t)row * DD;
    const float* tp = tgt + (size_t)row * DD;

    float vals[3];
    float s = 0.f;
    #pragma unroll
    for (int i = 0; i < 3; ++i) {
        const float v = xp[tid + i * 256] + tp[tid + i * 256];
        vals[i] = v;
        s += v;
    }
    s = block_sum(s, red, tid);
    const float mu = s * (1.f / 768.f);

    float vs = 0.f;
    #pragma unroll
    for (int i = 0; i < 3; ++i) {
        const float dv = vals[i] - mu;
        vs += dv * dv;
    }
    vs = block_sum(vs, red, tid);
    const float rstd = rsqrtf(vs * (1.f / 768.f) + LN_EPS);

    #pragma unroll
    for (int i = 0; i < 3; ++i) {
        const int cidx = tid + i * 256;
        out[(size_t)row * DD + cidx] = g[cidx] * (vals[i] - mu) * rstd + bta[cidx];
    }
}

// ---------------- launch -----------------------------------------------------
extern "C" void kernel_launch(void* const* d_in, const int* in_sizes, int n_in,
                              void* d_out, int out_size, void* d_ws, size_t ws_size,
                              hipStream_t stream) {
    const float* tgt   = (const float*)d_in[0];
    const float* qpos  = (const float*)d_in[1];
    const float* ploc  = (const float*)d_in[2];
    const float* Wq    = (const float*)d_in[3];
    const float* bq    = (const float*)d_in[4];
    const float* Wk    = (const float*)d_in[5];
    const float* bk    = (const float*)d_in[6];
    const float* Wv    = (const float*)d_in[7];
    const float* bv    = (const float*)d_in[8];
    const float* Wo    = (const float*)d_in[9];
    const float* bo    = (const float*)d_in[10];
    const float* Wloc  = (const float*)d_in[11];
    const float* bloc  = (const float*)d_in[12];
    const float* ln_g  = (const float*)d_in[13];
    const float* ln_b  = (const float*)d_in[14];

    const size_t NQ = (size_t)MM * DD;           // 6291456
    const size_t NW = (size_t)DD * DD;           // 589824
    const size_t NB = (size_t)BB * HH * LL * LL; // 50331648

    short* qb   = (short*)d_ws;
    short* kb   = qb  + NQ;
    short* vtb  = kb  + NQ;
    short* aob  = vtb + NQ;
    short* aqk  = aob + NQ;
    short* av   = aqk + NQ;
    float* pbuf = (float*)aqk;                   // alias (aqk,av dead by then)
    short* wqt  = av + NQ;
    short* wkt  = wqt + NW;
    short* wvt  = wkt + NW;
    short* wot  = wvt + NW;
    short* lab  = wot + NW;

    const size_t needed = (size_t)(6 * NQ + 4 * NW + NB) * 2;
    const bool pre = (ws_size >= needed);

    if (pre)
        prep_kernel<true ><<<5696, 256, 0, stream>>>(tgt, qpos, ploc, Wloc, bloc,
                                                     Wq, Wk, Wv, Wo,
                                                     aqk, av, lab, wqt, wkt, wvt, wot);
    else
        prep_kernel<false><<<3648, 256, 0, stream>>>(tgt, qpos, ploc, Wloc, bloc,
                                                     Wq, Wk, Wv, Wo,
                                                     aqk, av, lab, wqt, wkt, wvt, wot);

    gemm_qkv<<<dim3(18, 64), 256, 0, stream>>>(aqk, av, wqt, bq, qb,
                                               wkt, bk, kb, wvt, bv, vtb);

    if (pre)
        attn_mfma<true ><<<dim3(192, 8), 256, 0, stream>>>(qb, kb, vtb, lab, ploc, Wloc, bloc, aob);
    else
        attn_mfma<false><<<dim3(192, 8), 256, 0, stream>>>(qb, kb, vtb, nullptr, ploc, Wloc, bloc, aob);

    gemm_o<<<dim3(6, 64), 256, 0, stream>>>(aob, wot, bo, pbuf);

    ln_kernel<<<MM, 256, 0, stream>>>(pbuf, tgt, ln_g, ln_b, (float*)d_out);
}